// Round 15
// baseline (183.482 us; speedup 1.0000x reference)
//
#include <hip/hip_runtime.h>

typedef __attribute__((ext_vector_type(8))) short bf16x8;
typedef __attribute__((ext_vector_type(4))) float f32x4;

#define IN_F 256
#define HF 128      // NUM_HEADS * OUT_FEATS
#define NHEADS 4
#define NEG 0.2f

// ---- CSR-build via two-level counting sort ----
#define RB 256      // nodes per bucket (dst>>8)
#define NBP 200     // padded bucket count; NBP-1 = dead bucket for tail edges
#define CHUNK 6400  // edges per part-block (25 per thread)
#define ITPT 25
#define BCAP 10000  // max edges per bucket (mean 8192, sigma~90 -> +20 sigma)

__device__ __forceinline__ unsigned short f2bf(float x) {
    unsigned u = __float_as_uint(x);
    unsigned r = (u + 0x7FFFu + ((u >> 16) & 1u)) >> 16;  // RNE
    return (unsigned short)r;
}
__device__ __forceinline__ float bf2f(unsigned short b) {
    return __uint_as_float((unsigned)b << 16);
}

// ---------------- W fp32 -> bf16 (done once) ----------------
__global__ __launch_bounds__(256) void wconv_kernel(const float* __restrict__ W,
                                                    unsigned short* __restrict__ Wb) {
    int i = (blockIdx.x * 256 + threadIdx.x) * 4;
    if (i < HF * IN_F) {
        float4 v = *(const float4*)&W[i];
        ushort4 o;
        o.x = f2bf(v.x); o.y = f2bf(v.y); o.z = f2bf(v.z); o.w = f2bf(v.w);
        *(ushort4*)&Wb[i] = o;
    }
}

// ---------------- streaming GEMM: block = 64 rows, wave = 32 cols (1 head) ----
__global__ __launch_bounds__(256) void gemm_kernel(
    const float* __restrict__ feat, const unsigned short* __restrict__ Wb,
    const float* __restrict__ al, const float* __restrict__ ar,
    unsigned short* __restrict__ hb, float* __restrict__ el, float* __restrict__ er,
    int N)
{
    __shared__ char smem[64 * 256 * 2];   // 32 KB bf16 tile, XOR-swizzled
    const int t = threadIdx.x;
    const int lane = t & 63;
    const int wid = t >> 6;               // wave id == head id (cols wid*32..+31)
    const int n0 = blockIdx.x * 64;
    const int lr = lane & 15;
    const int lkO = (lane >> 4) * 8;      // k-offset within a 32-wide K slice

    bf16x8 b[2][8];
#pragma unroll
    for (int nj = 0; nj < 2; nj++)
#pragma unroll
        for (int ks = 0; ks < 8; ks++)
            b[nj][ks] = *(const bf16x8*)&Wb[(size_t)(wid * 32 + nj * 16 + lr) * IN_F + ks * 32 + lkO];

    const float4 z4 = make_float4(0.f, 0.f, 0.f, 0.f);
#pragma unroll
    for (int i = 0; i < 16; i++) {
        int flat = i * 1024 + t * 4;      // element in 64x256 tile
        int row = flat >> 8;
        int col = flat & 255;
        int n = n0 + row;
        float4 v = (n < N) ? *(const float4*)&feat[(size_t)n * IN_F + col] : z4;
        ushort4 s;
        s.x = f2bf(v.x); s.y = f2bf(v.y); s.z = f2bf(v.z); s.w = f2bf(v.w);
        int byte = (row * 512 + col * 2) ^ ((row & 7) << 4);
        *(ushort4*)(smem + byte) = s;
    }
    __syncthreads();

    f32x4 acc[4][2];
#pragma unroll
    for (int mi = 0; mi < 4; mi++)
#pragma unroll
        for (int nj = 0; nj < 2; nj++) acc[mi][nj] = (f32x4){0.f, 0.f, 0.f, 0.f};

#pragma unroll
    for (int mi = 0; mi < 4; mi++) {
        const int r = mi * 16 + lr;
#pragma unroll
        for (int ks = 0; ks < 8; ks++) {
            int byte = (r * 512 + (ks * 32 + lkO) * 2) ^ ((r & 7) << 4);
            bf16x8 a = *(const bf16x8*)(smem + byte);
            acc[mi][0] = __builtin_amdgcn_mfma_f32_16x16x32_bf16(a, b[0][ks], acc[mi][0], 0, 0, 0);
            acc[mi][1] = __builtin_amdgcn_mfma_f32_16x16x32_bf16(a, b[1][ks], acc[mi][1], 0, 0, 0);
        }
    }

    float alc0 = al[wid * 32 + lr],      arc0 = ar[wid * 32 + lr];
    float alc1 = al[wid * 32 + 16 + lr], arc1 = ar[wid * 32 + 16 + lr];
    const int crow = (lane >> 4) * 4;
#pragma unroll
    for (int mi = 0; mi < 4; mi++)
#pragma unroll
        for (int j = 0; j < 4; j++) {
            int n = n0 + mi * 16 + crow + j;
            if (n < N) {
                hb[(size_t)n * HF + wid * 32 + lr]      = f2bf(acc[mi][0][j]);
                hb[(size_t)n * HF + wid * 32 + 16 + lr] = f2bf(acc[mi][1][j]);
            }
            float e = acc[mi][0][j] * alc0 + acc[mi][1][j] * alc1;
            float r2 = acc[mi][0][j] * arc0 + acc[mi][1][j] * arc1;
#pragma unroll
            for (int off = 1; off < 16; off <<= 1) {
                e += __shfl_xor(e, off);
                r2 += __shfl_xor(r2, off);
            }
            if (lr == 0 && n < N) {
                el[n * 4 + wid] = e;
                er[n * 4 + wid] = r2;
            }
        }
}

// ---------------- P3 (v1): partition edges into coarse buckets, coalesced ----
__global__ __launch_bounds__(256) void part_kernel(const int* __restrict__ src,
                                                   const int* __restrict__ dst,
                                                   int* __restrict__ ebuf,
                                                   int* __restrict__ cntArr,
                                                   int* __restrict__ ofsArr, int E) {
    __shared__ int cnt[256];
    __shared__ int sc[256];
    __shared__ int cur[256];
    __shared__ int stage[CHUNK];
    const int blk = blockIdx.x, t = threadIdx.x;
    const int eb = blk * CHUNK;
    cnt[t] = 0;
    __syncthreads();

    int bkt[ITPT], ent[ITPT];
#pragma unroll
    for (int i = 0; i < ITPT; i++) {
        int idx = eb + i * 256 + t;
        int b = NBP - 1, e = 0;
        if (idx < E) {
            int d = dst[idx];
            int s = src[idx];
            b = d >> 8;
            e = s | ((d & 255) << 24);
        }
        bkt[i] = b;
        ent[i] = e;
        atomicAdd(&cnt[b], 1);
    }
    __syncthreads();
    int orig = cnt[t];
    sc[t] = orig;
    __syncthreads();
    for (int off = 1; off < 256; off <<= 1) {
        int v = (t >= off) ? sc[t - off] : 0;
        __syncthreads();
        sc[t] += v;
        __syncthreads();
    }
    int excl = sc[t] - orig;
    if (t < NBP) {
        cntArr[blk * NBP + t] = orig;
        ofsArr[blk * NBP + t] = excl;
    }
    cur[t] = excl;
    __syncthreads();
#pragma unroll
    for (int i = 0; i < ITPT; i++) {
        int pos = atomicAdd(&cur[bkt[i]], 1);
        stage[pos] = ent[i];
    }
    __syncthreads();
#pragma unroll
    for (int i = 0; i < ITPT; i++) {
        int idx = i * 256 + t;
        ebuf[eb + idx] = stage[idx];
    }
}

// ---------------- P3.5: scan bucket totals -> bucketStart ----------------
__global__ __launch_bounds__(256) void bscan_kernel(const int* __restrict__ cntArr,
                                                    int* __restrict__ bucketStart, int nblk) {
    __shared__ int sums[256];
    const int t = threadIdx.x;
    int s = 0;
    if (t < NBP)
        for (int blk = 0; blk < nblk; blk++) s += cntArr[blk * NBP + t];
    sums[t] = s;
    __syncthreads();
    for (int off = 1; off < 256; off <<= 1) {
        int v = (t >= off) ? sums[t - off] : 0;
        __syncthreads();
        sums[t] += v;
        __syncthreads();
    }
    if (t < NBP) bucketStart[t] = sums[t] - s;
}

// ---------------- P4: per-bucket counting sort -> esrc + rowStart ----------
__global__ __launch_bounds__(256) void bsort_kernel(const int* __restrict__ ebuf,
                                                    const int* __restrict__ cntArr,
                                                    const int* __restrict__ ofsArr,
                                                    const int* __restrict__ bucketStart,
                                                    int* __restrict__ rowStart,
                                                    int* __restrict__ esrc,
                                                    int nblk, int N, int E) {
    __shared__ int lcnt[256];
    __shared__ int lsc[256];
    __shared__ int lcur[256];
    __shared__ int sorted[BCAP];
    const int b = blockIdx.x, t = threadIdx.x;
    const int gbase = bucketStart[b];
    lcnt[t] = 0;
    __syncthreads();

    int rbase = 0, rlen = 0;
    if (t < nblk) {
        rbase = t * CHUNK + ofsArr[t * NBP + b];
        rlen = cntArr[t * NBP + b];
    }
    int i = 0;
    for (; i + 3 < rlen; i += 4) {
        unsigned e0 = (unsigned)ebuf[rbase + i];
        unsigned e1 = (unsigned)ebuf[rbase + i + 1];
        unsigned e2 = (unsigned)ebuf[rbase + i + 2];
        unsigned e3 = (unsigned)ebuf[rbase + i + 3];
        atomicAdd(&lcnt[e0 >> 24], 1);
        atomicAdd(&lcnt[e1 >> 24], 1);
        atomicAdd(&lcnt[e2 >> 24], 1);
        atomicAdd(&lcnt[e3 >> 24], 1);
    }
    for (; i < rlen; i++) {
        unsigned e = (unsigned)ebuf[rbase + i];
        atomicAdd(&lcnt[e >> 24], 1);
    }
    __syncthreads();
    int orig = lcnt[t];
    lsc[t] = orig;
    __syncthreads();
    for (int off = 1; off < 256; off <<= 1) {
        int v = (t >= off) ? lsc[t - off] : 0;
        __syncthreads();
        lsc[t] += v;
        __syncthreads();
    }
    int excl = lsc[t] - orig;
    int node = b * RB + t;
    if (node < N) rowStart[node] = gbase + excl;
    if (b == 0 && t == 0) rowStart[N] = E;
    lcur[t] = excl;
    __syncthreads();
    i = 0;
    for (; i + 3 < rlen; i += 4) {
        unsigned e0 = (unsigned)ebuf[rbase + i];
        unsigned e1 = (unsigned)ebuf[rbase + i + 1];
        unsigned e2 = (unsigned)ebuf[rbase + i + 2];
        unsigned e3 = (unsigned)ebuf[rbase + i + 3];
        sorted[atomicAdd(&lcur[e0 >> 24], 1)] = (int)(e0 & 0xFFFFFFu);
        sorted[atomicAdd(&lcur[e1 >> 24], 1)] = (int)(e1 & 0xFFFFFFu);
        sorted[atomicAdd(&lcur[e2 >> 24], 1)] = (int)(e2 & 0xFFFFFFu);
        sorted[atomicAdd(&lcur[e3 >> 24], 1)] = (int)(e3 & 0xFFFFFFu);
    }
    for (; i < rlen; i++) {
        unsigned e = (unsigned)ebuf[rbase + i];
        sorted[atomicAdd(&lcur[e >> 24], 1)] = (int)(e & 0xFFFFFFu);
    }
    __syncthreads();
    const int total = lsc[255];
    for (int k = t; k < total; k += 256) esrc[gbase + k] = sorted[k];
}

// ---------------- agg: one wave per dst node, software-pipelined gather ------
// 16 lanes per edge-row (uint4 = 16B/lane), 4 edges in flight per wave;
// next-iter {esrc, hb, el} loads issued before current-iter compute (G15/T14).
__global__ __launch_bounds__(256) void agg_kernel(const int* __restrict__ rowStart,
                                                  const int* __restrict__ esrc,
                                                  const unsigned short* __restrict__ hb,
                                                  const float* __restrict__ el,
                                                  const float* __restrict__ er,
                                                  const float* __restrict__ bias,
                                                  float* __restrict__ out,
                                                  int n_lo, int n_hi) {
    const int wid = threadIdx.x >> 6;
    const int lane = threadIdx.x & 63;
    const int n = n_lo + blockIdx.x * 4 + wid;
    if (n >= n_hi) return;
    const int lg = lane & 15;
    const int grp = lane >> 4;
    const int head = lg >> 2;
    const float ern = er[n * NHEADS + head];
    const int beg = rowStart[n];
    const int end = rowStart[n + 1];

    float acc[8];
#pragma unroll
    for (int i = 0; i < 8; i++) acc[i] = 0.f;
    float den = 0.f;

    int j = beg + grp;
    const uint4 zu4 = make_uint4(0u, 0u, 0u, 0u);
    // prologue: loads for first iteration
    int s = (j < end) ? esrc[j] : -1;
    uint4 hv = (s >= 0) ? *(const uint4*)&hb[(size_t)s * HF + lg * 8] : zu4;
    float elv = (s >= 0) ? el[s * NHEADS + head] : 0.f;

    while (j < end) {
        // issue next-iteration loads first (independent of current compute)
        int jn = j + 4;
        int sn = (jn < end) ? esrc[jn] : -1;
        uint4 hvn = (sn >= 0) ? *(const uint4*)&hb[(size_t)sn * HF + lg * 8] : zu4;
        float elvn = (sn >= 0) ? el[sn * NHEADS + head] : 0.f;
        // compute current
        float x = elv + ern;
        x = x >= 0.f ? x : NEG * x;
        float sv = (s >= 0) ? __expf(x) : 0.f;
        acc[0] += sv * bf2f((unsigned short)(hv.x & 0xFFFFu));
        acc[1] += sv * bf2f((unsigned short)(hv.x >> 16));
        acc[2] += sv * bf2f((unsigned short)(hv.y & 0xFFFFu));
        acc[3] += sv * bf2f((unsigned short)(hv.y >> 16));
        acc[4] += sv * bf2f((unsigned short)(hv.z & 0xFFFFu));
        acc[5] += sv * bf2f((unsigned short)(hv.z >> 16));
        acc[6] += sv * bf2f((unsigned short)(hv.w & 0xFFFFu));
        acc[7] += sv * bf2f((unsigned short)(hv.w >> 16));
        den += sv;
        // rotate
        j = jn; s = sn; hv = hvn; elv = elvn;
    }

#pragma unroll
    for (int off = 16; off < 64; off <<= 1) {
#pragma unroll
        for (int i = 0; i < 8; i++) acc[i] += __shfl_xor(acc[i], off);
        den += __shfl_xor(den, off);
    }

    if (lane < 16) {
        float inv = 1.f / (den > 0.f ? den : 1.f);
        float4 b0 = *(const float4*)&bias[lg * 8];
        float4 b1 = *(const float4*)&bias[lg * 8 + 4];
        float4 o0, o1;
        o0.x = acc[0] * inv + b0.x; o0.y = acc[1] * inv + b0.y;
        o0.z = acc[2] * inv + b0.z; o0.w = acc[3] * inv + b0.w;
        o1.x = acc[4] * inv + b1.x; o1.y = acc[5] * inv + b1.y;
        o1.z = acc[6] * inv + b1.z; o1.w = acc[7] * inv + b1.w;
        *(float4*)&out[(size_t)n * HF + lg * 8] = o0;
        *(float4*)&out[(size_t)n * HF + lg * 8 + 4] = o1;
    }
}

extern "C" void kernel_launch(void* const* d_in, const int* in_sizes, int n_in,
                              void* d_out, int out_size, void* d_ws, size_t ws_size,
                              hipStream_t stream) {
    const float* feat = (const float*)d_in[0];
    const float* W    = (const float*)d_in[1];
    const float* al   = (const float*)d_in[2];
    const float* ar   = (const float*)d_in[3];
    const float* bias = (const float*)d_in[4];
    const int*   src  = (const int*)d_in[5];
    const int*   dst  = (const int*)d_in[6];
    const int N = in_sizes[0] / IN_F;
    const int E = in_sizes[5];
    float* out = (float*)d_out;

    const int nblk = (E + CHUNK - 1) / CHUNK;    // 250 for E=1.6M (must be <= 256)
    const int NBUCK = (N + RB - 1) / RB;         // 196 for N=50000 (must be <= NBP-1)

    unsigned short* hb = (unsigned short*)d_ws;              // N*128 bf16
    unsigned short* Wb = hb + (size_t)N * HF;                // 128*256 bf16
    float* el       = (float*)(Wb + HF * IN_F);              // N*4 f32
    float* er       = el + (size_t)N * NHEADS;               // N*4
    int* rowStart   = (int*)(er + (size_t)N * NHEADS);       // N+1
    int* esrc       = rowStart + (N + 1);                    // E
    int* ebuf       = esrc + E;                              // nblk*CHUNK
    int* cntArr     = ebuf + (size_t)nblk * CHUNK;           // nblk*NBP
    int* ofsArr     = cntArr + (size_t)nblk * NBP;           // nblk*NBP
    int* bucketStart= ofsArr + (size_t)nblk * NBP;           // NBP+1

    const int Nh = (N + 1) / 2;   // split agg for top-5 attribution

    wconv_kernel<<<(HF * IN_F / 4 + 255) / 256, 256, 0, stream>>>(W, Wb);
    part_kernel<<<nblk, 256, 0, stream>>>(src, dst, ebuf, cntArr, ofsArr, E);
    gemm_kernel<<<(N + 63) / 64, 256, 0, stream>>>(feat, Wb, al, ar, hb, el, er, N);
    bscan_kernel<<<1, 256, 0, stream>>>(cntArr, bucketStart, nblk);
    bsort_kernel<<<NBUCK, 256, 0, stream>>>(ebuf, cntArr, ofsArr, bucketStart,
                                            rowStart, esrc, nblk, N, E);
    agg_kernel<<<(Nh + 3) / 4, 256, 0, stream>>>(rowStart, esrc, hb, el, er, bias, out, 0, Nh);
    agg_kernel<<<(N - Nh + 3) / 4, 256, 0, stream>>>(rowStart, esrc, hb, el, er, bias, out, Nh, N);
}

// Round 16
// 157.986 us; speedup vs baseline: 1.1614x; 1.1614x over previous
//
#include <hip/hip_runtime.h>

typedef __attribute__((ext_vector_type(8))) short bf16x8;
typedef __attribute__((ext_vector_type(4))) float f32x4;

#define IN_F 256
#define HF 128      // NUM_HEADS * OUT_FEATS
#define NHEADS 4
#define NEG 0.2f

// ---- CSR-build via two-level counting sort ----
#define RB 256      // nodes per bucket (dst>>8)
#define NBP 200     // padded bucket count; NBP-1 = dead bucket for tail edges
#define CHUNK 6400  // edges per part-block (25 per thread)
#define ITPT 25
#define BCAP 10000  // max edges per bucket (mean 8192, sigma~90 -> +20 sigma)

__device__ __forceinline__ unsigned short f2bf(float x) {
    unsigned u = __float_as_uint(x);
    unsigned r = (u + 0x7FFFu + ((u >> 16) & 1u)) >> 16;  // RNE
    return (unsigned short)r;
}
__device__ __forceinline__ float bf2f(unsigned short b) {
    return __uint_as_float((unsigned)b << 16);
}

// ---------------- W fp32 -> bf16 (done once) ----------------
__global__ __launch_bounds__(256) void wconv_kernel(const float* __restrict__ W,
                                                    unsigned short* __restrict__ Wb) {
    int i = (blockIdx.x * 256 + threadIdx.x) * 4;
    if (i < HF * IN_F) {
        float4 v = *(const float4*)&W[i];
        ushort4 o;
        o.x = f2bf(v.x); o.y = f2bf(v.y); o.z = f2bf(v.z); o.w = f2bf(v.w);
        *(ushort4*)&Wb[i] = o;
    }
}

// ---------------- streaming GEMM: block = 64 rows, wave = 32 cols (1 head) ----
__global__ __launch_bounds__(256) void gemm_kernel(
    const float* __restrict__ feat, const unsigned short* __restrict__ Wb,
    const float* __restrict__ al, const float* __restrict__ ar,
    unsigned short* __restrict__ hb, float* __restrict__ el, float* __restrict__ er,
    int N)
{
    __shared__ char smem[64 * 256 * 2];   // 32 KB bf16 tile, XOR-swizzled
    const int t = threadIdx.x;
    const int lane = t & 63;
    const int wid = t >> 6;               // wave id == head id (cols wid*32..+31)
    const int n0 = blockIdx.x * 64;
    const int lr = lane & 15;
    const int lkO = (lane >> 4) * 8;      // k-offset within a 32-wide K slice

    bf16x8 b[2][8];
#pragma unroll
    for (int nj = 0; nj < 2; nj++)
#pragma unroll
        for (int ks = 0; ks < 8; ks++)
            b[nj][ks] = *(const bf16x8*)&Wb[(size_t)(wid * 32 + nj * 16 + lr) * IN_F + ks * 32 + lkO];

    const float4 z4 = make_float4(0.f, 0.f, 0.f, 0.f);
#pragma unroll
    for (int i = 0; i < 16; i++) {
        int flat = i * 1024 + t * 4;      // element in 64x256 tile
        int row = flat >> 8;
        int col = flat & 255;
        int n = n0 + row;
        float4 v = (n < N) ? *(const float4*)&feat[(size_t)n * IN_F + col] : z4;
        ushort4 s;
        s.x = f2bf(v.x); s.y = f2bf(v.y); s.z = f2bf(v.z); s.w = f2bf(v.w);
        int byte = (row * 512 + col * 2) ^ ((row & 7) << 4);
        *(ushort4*)(smem + byte) = s;
    }
    __syncthreads();

    f32x4 acc[4][2];
#pragma unroll
    for (int mi = 0; mi < 4; mi++)
#pragma unroll
        for (int nj = 0; nj < 2; nj++) acc[mi][nj] = (f32x4){0.f, 0.f, 0.f, 0.f};

#pragma unroll
    for (int mi = 0; mi < 4; mi++) {
        const int r = mi * 16 + lr;
#pragma unroll
        for (int ks = 0; ks < 8; ks++) {
            int byte = (r * 512 + (ks * 32 + lkO) * 2) ^ ((r & 7) << 4);
            bf16x8 a = *(const bf16x8*)(smem + byte);
            acc[mi][0] = __builtin_amdgcn_mfma_f32_16x16x32_bf16(a, b[0][ks], acc[mi][0], 0, 0, 0);
            acc[mi][1] = __builtin_amdgcn_mfma_f32_16x16x32_bf16(a, b[1][ks], acc[mi][1], 0, 0, 0);
        }
    }

    float alc0 = al[wid * 32 + lr],      arc0 = ar[wid * 32 + lr];
    float alc1 = al[wid * 32 + 16 + lr], arc1 = ar[wid * 32 + 16 + lr];
    const int crow = (lane >> 4) * 4;
#pragma unroll
    for (int mi = 0; mi < 4; mi++)
#pragma unroll
        for (int j = 0; j < 4; j++) {
            int n = n0 + mi * 16 + crow + j;
            if (n < N) {
                hb[(size_t)n * HF + wid * 32 + lr]      = f2bf(acc[mi][0][j]);
                hb[(size_t)n * HF + wid * 32 + 16 + lr] = f2bf(acc[mi][1][j]);
            }
            float e = acc[mi][0][j] * alc0 + acc[mi][1][j] * alc1;
            float r2 = acc[mi][0][j] * arc0 + acc[mi][1][j] * arc1;
#pragma unroll
            for (int off = 1; off < 16; off <<= 1) {
                e += __shfl_xor(e, off);
                r2 += __shfl_xor(r2, off);
            }
            if (lr == 0 && n < N) {
                el[n * 4 + wid] = e;
                er[n * 4 + wid] = r2;
            }
        }
}

// ---------------- P3 (v1): partition edges into coarse buckets, coalesced ----
__global__ __launch_bounds__(256) void part_kernel(const int* __restrict__ src,
                                                   const int* __restrict__ dst,
                                                   int* __restrict__ ebuf,
                                                   int* __restrict__ cntArr,
                                                   int* __restrict__ ofsArr, int E) {
    __shared__ int cnt[256];
    __shared__ int sc[256];
    __shared__ int cur[256];
    __shared__ int stage[CHUNK];
    const int blk = blockIdx.x, t = threadIdx.x;
    const int eb = blk * CHUNK;
    cnt[t] = 0;
    __syncthreads();

    int bkt[ITPT], ent[ITPT];
#pragma unroll
    for (int i = 0; i < ITPT; i++) {
        int idx = eb + i * 256 + t;
        int b = NBP - 1, e = 0;
        if (idx < E) {
            int d = dst[idx];
            int s = src[idx];
            b = d >> 8;
            e = s | ((d & 255) << 24);
        }
        bkt[i] = b;
        ent[i] = e;
        atomicAdd(&cnt[b], 1);
    }
    __syncthreads();
    int orig = cnt[t];
    sc[t] = orig;
    __syncthreads();
    for (int off = 1; off < 256; off <<= 1) {
        int v = (t >= off) ? sc[t - off] : 0;
        __syncthreads();
        sc[t] += v;
        __syncthreads();
    }
    int excl = sc[t] - orig;
    if (t < NBP) {
        cntArr[blk * NBP + t] = orig;
        ofsArr[blk * NBP + t] = excl;
    }
    cur[t] = excl;
    __syncthreads();
#pragma unroll
    for (int i = 0; i < ITPT; i++) {
        int pos = atomicAdd(&cur[bkt[i]], 1);
        stage[pos] = ent[i];
    }
    __syncthreads();
#pragma unroll
    for (int i = 0; i < ITPT; i++) {
        int idx = i * 256 + t;
        ebuf[eb + idx] = stage[idx];
    }
}

// ---------------- P3.5: scan bucket totals -> bucketStart ----------------
__global__ __launch_bounds__(256) void bscan_kernel(const int* __restrict__ cntArr,
                                                    int* __restrict__ bucketStart, int nblk) {
    __shared__ int sums[256];
    const int t = threadIdx.x;
    int s = 0;
    if (t < NBP)
        for (int blk = 0; blk < nblk; blk++) s += cntArr[blk * NBP + t];
    sums[t] = s;
    __syncthreads();
    for (int off = 1; off < 256; off <<= 1) {
        int v = (t >= off) ? sums[t - off] : 0;
        __syncthreads();
        sums[t] += v;
        __syncthreads();
    }
    if (t < NBP) bucketStart[t] = sums[t] - s;
}

// ---------------- P4: per-bucket counting sort -> esrc + rowStart ----------
__global__ __launch_bounds__(256) void bsort_kernel(const int* __restrict__ ebuf,
                                                    const int* __restrict__ cntArr,
                                                    const int* __restrict__ ofsArr,
                                                    const int* __restrict__ bucketStart,
                                                    int* __restrict__ rowStart,
                                                    int* __restrict__ esrc,
                                                    int nblk, int N, int E) {
    __shared__ int lcnt[256];
    __shared__ int lsc[256];
    __shared__ int lcur[256];
    __shared__ int sorted[BCAP];
    const int b = blockIdx.x, t = threadIdx.x;
    const int gbase = bucketStart[b];
    lcnt[t] = 0;
    __syncthreads();

    int rbase = 0, rlen = 0;
    if (t < nblk) {
        rbase = t * CHUNK + ofsArr[t * NBP + b];
        rlen = cntArr[t * NBP + b];
    }
    int i = 0;
    for (; i + 3 < rlen; i += 4) {
        unsigned e0 = (unsigned)ebuf[rbase + i];
        unsigned e1 = (unsigned)ebuf[rbase + i + 1];
        unsigned e2 = (unsigned)ebuf[rbase + i + 2];
        unsigned e3 = (unsigned)ebuf[rbase + i + 3];
        atomicAdd(&lcnt[e0 >> 24], 1);
        atomicAdd(&lcnt[e1 >> 24], 1);
        atomicAdd(&lcnt[e2 >> 24], 1);
        atomicAdd(&lcnt[e3 >> 24], 1);
    }
    for (; i < rlen; i++) {
        unsigned e = (unsigned)ebuf[rbase + i];
        atomicAdd(&lcnt[e >> 24], 1);
    }
    __syncthreads();
    int orig = lcnt[t];
    lsc[t] = orig;
    __syncthreads();
    for (int off = 1; off < 256; off <<= 1) {
        int v = (t >= off) ? lsc[t - off] : 0;
        __syncthreads();
        lsc[t] += v;
        __syncthreads();
    }
    int excl = lsc[t] - orig;
    int node = b * RB + t;
    if (node < N) rowStart[node] = gbase + excl;
    if (b == 0 && t == 0) rowStart[N] = E;
    lcur[t] = excl;
    __syncthreads();
    i = 0;
    for (; i + 3 < rlen; i += 4) {
        unsigned e0 = (unsigned)ebuf[rbase + i];
        unsigned e1 = (unsigned)ebuf[rbase + i + 1];
        unsigned e2 = (unsigned)ebuf[rbase + i + 2];
        unsigned e3 = (unsigned)ebuf[rbase + i + 3];
        sorted[atomicAdd(&lcur[e0 >> 24], 1)] = (int)(e0 & 0xFFFFFFu);
        sorted[atomicAdd(&lcur[e1 >> 24], 1)] = (int)(e1 & 0xFFFFFFu);
        sorted[atomicAdd(&lcur[e2 >> 24], 1)] = (int)(e2 & 0xFFFFFFu);
        sorted[atomicAdd(&lcur[e3 >> 24], 1)] = (int)(e3 & 0xFFFFFFu);
    }
    for (; i < rlen; i++) {
        unsigned e = (unsigned)ebuf[rbase + i];
        sorted[atomicAdd(&lcur[e >> 24], 1)] = (int)(e & 0xFFFFFFu);
    }
    __syncthreads();
    const int total = lsc[255];
    for (int k = t; k < total; k += 256) esrc[gbase + k] = sorted[k];
}

// ---------------- fused agg: one wave per dst node ----------------
// 16 lanes per edge-row (uint4 = 16B/lane), 4 edges in flight per wave;
// unroll 4 -> four independent esrc->hb chains in flight (compiler-scheduled).
__global__ __launch_bounds__(256) void agg_kernel(const int* __restrict__ rowStart,
                                                  const int* __restrict__ esrc,
                                                  const unsigned short* __restrict__ hb,
                                                  const float* __restrict__ el,
                                                  const float* __restrict__ er,
                                                  const float* __restrict__ bias,
                                                  float* __restrict__ out, int N) {
    const int wid = threadIdx.x >> 6;
    const int lane = threadIdx.x & 63;
    const int n = blockIdx.x * 4 + wid;
    if (n >= N) return;
    const int lg = lane & 15;
    const int grp = lane >> 4;
    const int head = lg >> 2;
    const float ern = er[n * NHEADS + head];
    const int beg = rowStart[n];
    const int end = rowStart[n + 1];

    float acc[8];
#pragma unroll
    for (int i = 0; i < 8; i++) acc[i] = 0.f;
    float den = 0.f;

#pragma unroll 4
    for (int j = beg + grp; j < end; j += 4) {
        int s = esrc[j];
        float x = el[s * NHEADS + head] + ern;
        x = x >= 0.f ? x : NEG * x;
        float sv = __expf(x);
        uint4 hv = *(const uint4*)&hb[(size_t)s * HF + lg * 8];
        acc[0] += sv * bf2f((unsigned short)(hv.x & 0xFFFFu));
        acc[1] += sv * bf2f((unsigned short)(hv.x >> 16));
        acc[2] += sv * bf2f((unsigned short)(hv.y & 0xFFFFu));
        acc[3] += sv * bf2f((unsigned short)(hv.y >> 16));
        acc[4] += sv * bf2f((unsigned short)(hv.z & 0xFFFFu));
        acc[5] += sv * bf2f((unsigned short)(hv.z >> 16));
        acc[6] += sv * bf2f((unsigned short)(hv.w & 0xFFFFu));
        acc[7] += sv * bf2f((unsigned short)(hv.w >> 16));
        den += sv;
    }

#pragma unroll
    for (int off = 16; off < 64; off <<= 1) {
#pragma unroll
        for (int i = 0; i < 8; i++) acc[i] += __shfl_xor(acc[i], off);
        den += __shfl_xor(den, off);
    }

    if (lane < 16) {
        float inv = 1.f / (den > 0.f ? den : 1.f);
        float4 b0 = *(const float4*)&bias[lg * 8];
        float4 b1 = *(const float4*)&bias[lg * 8 + 4];
        float4 o0, o1;
        o0.x = acc[0] * inv + b0.x; o0.y = acc[1] * inv + b0.y;
        o0.z = acc[2] * inv + b0.z; o0.w = acc[3] * inv + b0.w;
        o1.x = acc[4] * inv + b1.x; o1.y = acc[5] * inv + b1.y;
        o1.z = acc[6] * inv + b1.z; o1.w = acc[7] * inv + b1.w;
        *(float4*)&out[(size_t)n * HF + lg * 8] = o0;
        *(float4*)&out[(size_t)n * HF + lg * 8 + 4] = o1;
    }
}

extern "C" void kernel_launch(void* const* d_in, const int* in_sizes, int n_in,
                              void* d_out, int out_size, void* d_ws, size_t ws_size,
                              hipStream_t stream) {
    const float* feat = (const float*)d_in[0];
    const float* W    = (const float*)d_in[1];
    const float* al   = (const float*)d_in[2];
    const float* ar   = (const float*)d_in[3];
    const float* bias = (const float*)d_in[4];
    const int*   src  = (const int*)d_in[5];
    const int*   dst  = (const int*)d_in[6];
    const int N = in_sizes[0] / IN_F;
    const int E = in_sizes[5];
    float* out = (float*)d_out;

    const int nblk = (E + CHUNK - 1) / CHUNK;    // 250 for E=1.6M (must be <= 256)
    const int NBUCK = (N + RB - 1) / RB;         // 196 for N=50000 (must be <= NBP-1)

    unsigned short* hb = (unsigned short*)d_ws;              // N*128 bf16
    unsigned short* Wb = hb + (size_t)N * HF;                // 128*256 bf16
    float* el       = (float*)(Wb + HF * IN_F);              // N*4 f32
    float* er       = el + (size_t)N * NHEADS;               // N*4
    int* rowStart   = (int*)(er + (size_t)N * NHEADS);       // N+1
    int* esrc       = rowStart + (N + 1);                    // E
    int* ebuf       = esrc + E;                              // nblk*CHUNK
    int* cntArr     = ebuf + (size_t)nblk * CHUNK;           // nblk*NBP
    int* ofsArr     = cntArr + (size_t)nblk * NBP;           // nblk*NBP
    int* bucketStart= ofsArr + (size_t)nblk * NBP;           // NBP+1

    wconv_kernel<<<(HF * IN_F / 4 + 255) / 256, 256, 0, stream>>>(W, Wb);
    part_kernel<<<nblk, 256, 0, stream>>>(src, dst, ebuf, cntArr, ofsArr, E);
    gemm_kernel<<<(N + 63) / 64, 256, 0, stream>>>(feat, Wb, al, ar, hb, el, er, N);
    bscan_kernel<<<1, 256, 0, stream>>>(cntArr, bucketStart, nblk);
    bsort_kernel<<<NBUCK, 256, 0, stream>>>(ebuf, cntArr, ofsArr, bucketStart,
                                            rowStart, esrc, nblk, N, E);
    agg_kernel<<<(N + 3) / 4, 256, 0, stream>>>(rowStart, esrc, hb, el, er, bias, out, N);
}

// Round 18
// 153.402 us; speedup vs baseline: 1.1961x; 1.0299x over previous
//
#include <hip/hip_runtime.h>

typedef __attribute__((ext_vector_type(8))) short bf16x8;
typedef __attribute__((ext_vector_type(4))) float f32x4;

#define IN_F 256
#define HF 128      // NUM_HEADS * OUT_FEATS
#define NHEADS 4
#define NEG 0.2f

// ---- CSR-build via two-level counting sort ----
#define RB 256      // nodes per bucket (dst>>8)
#define NBP 200     // padded bucket count; NBP-1 = dead bucket for tail edges
#define CHUNK 6400  // edges per part-block (25 per thread)
#define ITPT 25
#define BCAP 10000  // max edges per bucket (mean 8192, sigma~90 -> +20 sigma)

#define K1_SMEM 32768   // max(gemm 64*256*2, part (768+CHUNK)*4)

__device__ __forceinline__ unsigned short f2bf(float x) {
    unsigned u = __float_as_uint(x);
    unsigned r = (u + 0x7FFFu + ((u >> 16) & 1u)) >> 16;  // RNE
    return (unsigned short)r;
}
__device__ __forceinline__ float bf2f(unsigned short b) {
    return __uint_as_float((unsigned)b << 16);
}
__device__ __forceinline__ bf16x8 cvt8(float4 x, float4 y) {
    bf16x8 r;
    r[0] = f2bf(x.x); r[1] = f2bf(x.y); r[2] = f2bf(x.z); r[3] = f2bf(x.w);
    r[4] = f2bf(y.x); r[5] = f2bf(y.y); r[6] = f2bf(y.z); r[7] = f2bf(y.w);
    return r;
}

// ============ fused K1 ============
// blocks < GG : streaming GEMM (64 rows/block, wave = 1 head), inline W cvt
// blocks >= GG: edge partition into coarse buckets
__global__ __launch_bounds__(256) void fused1_kernel(
    const float* __restrict__ feat, const float* __restrict__ W,
    const float* __restrict__ al, const float* __restrict__ ar,
    unsigned short* __restrict__ hb, float* __restrict__ el, float* __restrict__ er,
    const int* __restrict__ src, const int* __restrict__ dst,
    int* __restrict__ ebuf, int* __restrict__ cntArr, int* __restrict__ ofsArr,
    int N, int E, int GG)
{
    extern __shared__ char smem[];
    const int t = threadIdx.x;

    if ((int)blockIdx.x < GG) {
        // ---------------- GEMM branch ----------------
        const int lane = t & 63;
        const int wid = t >> 6;               // wave id == head id
        const int n0 = blockIdx.x * 64;
        const int lr = lane & 15;
        const int lkO = (lane >> 4) * 8;

        // B fragments: inline fp32->bf16 from L2-hot W (128 KB)
        bf16x8 b[2][8];
#pragma unroll
        for (int nj = 0; nj < 2; nj++)
#pragma unroll
            for (int ks = 0; ks < 8; ks++) {
                const float* wrow = &W[(size_t)(wid * 32 + nj * 16 + lr) * IN_F + ks * 32 + lkO];
                b[nj][ks] = cvt8(*(const float4*)wrow, *(const float4*)(wrow + 4));
            }

        const float4 z4 = make_float4(0.f, 0.f, 0.f, 0.f);
#pragma unroll
        for (int i = 0; i < 16; i++) {
            int flat = i * 1024 + t * 4;
            int row = flat >> 8;
            int col = flat & 255;
            int n = n0 + row;
            float4 v = (n < N) ? *(const float4*)&feat[(size_t)n * IN_F + col] : z4;
            ushort4 s;
            s.x = f2bf(v.x); s.y = f2bf(v.y); s.z = f2bf(v.z); s.w = f2bf(v.w);
            int byte = (row * 512 + col * 2) ^ ((row & 7) << 4);
            *(ushort4*)(smem + byte) = s;
        }
        __syncthreads();

        f32x4 acc[4][2];
#pragma unroll
        for (int mi = 0; mi < 4; mi++)
#pragma unroll
            for (int nj = 0; nj < 2; nj++) acc[mi][nj] = (f32x4){0.f, 0.f, 0.f, 0.f};

#pragma unroll
        for (int mi = 0; mi < 4; mi++) {
            const int r = mi * 16 + lr;
#pragma unroll
            for (int ks = 0; ks < 8; ks++) {
                int byte = (r * 512 + (ks * 32 + lkO) * 2) ^ ((r & 7) << 4);
                bf16x8 a = *(const bf16x8*)(smem + byte);
                acc[mi][0] = __builtin_amdgcn_mfma_f32_16x16x32_bf16(a, b[0][ks], acc[mi][0], 0, 0, 0);
                acc[mi][1] = __builtin_amdgcn_mfma_f32_16x16x32_bf16(a, b[1][ks], acc[mi][1], 0, 0, 0);
            }
        }

        float alc0 = al[wid * 32 + lr],      arc0 = ar[wid * 32 + lr];
        float alc1 = al[wid * 32 + 16 + lr], arc1 = ar[wid * 32 + 16 + lr];
        const int crow = (lane >> 4) * 4;
#pragma unroll
        for (int mi = 0; mi < 4; mi++)
#pragma unroll
            for (int j = 0; j < 4; j++) {
                int n = n0 + mi * 16 + crow + j;
                if (n < N) {
                    hb[(size_t)n * HF + wid * 32 + lr]      = f2bf(acc[mi][0][j]);
                    hb[(size_t)n * HF + wid * 32 + 16 + lr] = f2bf(acc[mi][1][j]);
                }
                float e = acc[mi][0][j] * alc0 + acc[mi][1][j] * alc1;
                float r2 = acc[mi][0][j] * arc0 + acc[mi][1][j] * arc1;
#pragma unroll
                for (int off = 1; off < 16; off <<= 1) {
                    e += __shfl_xor(e, off);
                    r2 += __shfl_xor(r2, off);
                }
                if (lr == 0 && n < N) {
                    el[n * 4 + wid] = e;
                    er[n * 4 + wid] = r2;
                }
            }
    } else {
        // ---------------- partition branch ----------------
        int* cnt = (int*)smem;            // 256
        int* sc  = cnt + 256;             // 256
        int* cur = sc + 256;              // 256
        int* stage = cur + 256;           // CHUNK
        const int blk = blockIdx.x - GG;
        const int eb = blk * CHUNK;
        cnt[t] = 0;
        __syncthreads();

        int bkt[ITPT], ent[ITPT];
#pragma unroll
        for (int i = 0; i < ITPT; i++) {
            int idx = eb + i * 256 + t;
            int b = NBP - 1, e = 0;
            if (idx < E) {
                int d = dst[idx];
                int s = src[idx];
                b = d >> 8;
                e = s | ((d & 255) << 24);
            }
            bkt[i] = b;
            ent[i] = e;
            atomicAdd(&cnt[b], 1);
        }
        __syncthreads();
        int orig = cnt[t];
        sc[t] = orig;
        __syncthreads();
        for (int off = 1; off < 256; off <<= 1) {
            int v = (t >= off) ? sc[t - off] : 0;
            __syncthreads();
            sc[t] += v;
            __syncthreads();
        }
        int excl = sc[t] - orig;
        if (t < NBP) {
            cntArr[blk * NBP + t] = orig;
            ofsArr[blk * NBP + t] = excl;
        }
        cur[t] = excl;
        __syncthreads();
#pragma unroll
        for (int i = 0; i < ITPT; i++) {
            int pos = atomicAdd(&cur[bkt[i]], 1);
            stage[pos] = ent[i];
        }
        __syncthreads();
#pragma unroll
        for (int i = 0; i < ITPT; i++) {
            int idx = i * 256 + t;
            ebuf[eb + idx] = stage[idx];
        }
    }
}

// ---------------- P4: per-bucket counting sort (self-computed gbase) --------
__global__ __launch_bounds__(256) void bsort_kernel(const int* __restrict__ ebuf,
                                                    const int* __restrict__ cntArr,
                                                    const int* __restrict__ ofsArr,
                                                    int* __restrict__ rowStart,
                                                    int* __restrict__ esrc,
                                                    int nblk, int N, int E) {
    __shared__ int lcnt[256];
    __shared__ int lsc[256];
    __shared__ int lcur[256];
    __shared__ int gbase_sh;
    __shared__ int sorted[BCAP];
    const int b = blockIdx.x, t = threadIdx.x;

    // phase 0: bucket totals over all chunks -> exclusive scan -> gbase
    int tot = 0;
    if (t < NBP)
        for (int blk = 0; blk < nblk; blk++) tot += cntArr[blk * NBP + t];
    lsc[t] = tot;
    __syncthreads();
    for (int off = 1; off < 256; off <<= 1) {
        int v = (t >= off) ? lsc[t - off] : 0;
        __syncthreads();
        lsc[t] += v;
        __syncthreads();
    }
    if (t == b) gbase_sh = lsc[t] - tot;
    lcnt[t] = 0;
    __syncthreads();
    const int gbase = gbase_sh;

    int rbase = 0, rlen = 0;
    if (t < nblk) {
        rbase = t * CHUNK + ofsArr[t * NBP + b];
        rlen = cntArr[t * NBP + b];
    }
    int i = 0;
    for (; i + 3 < rlen; i += 4) {
        unsigned e0 = (unsigned)ebuf[rbase + i];
        unsigned e1 = (unsigned)ebuf[rbase + i + 1];
        unsigned e2 = (unsigned)ebuf[rbase + i + 2];
        unsigned e3 = (unsigned)ebuf[rbase + i + 3];
        atomicAdd(&lcnt[e0 >> 24], 1);
        atomicAdd(&lcnt[e1 >> 24], 1);
        atomicAdd(&lcnt[e2 >> 24], 1);
        atomicAdd(&lcnt[e3 >> 24], 1);
    }
    for (; i < rlen; i++) {
        unsigned e = (unsigned)ebuf[rbase + i];
        atomicAdd(&lcnt[e >> 24], 1);
    }
    __syncthreads();
    int orig = lcnt[t];
    lsc[t] = orig;
    __syncthreads();
    for (int off = 1; off < 256; off <<= 1) {
        int v = (t >= off) ? lsc[t - off] : 0;
        __syncthreads();
        lsc[t] += v;
        __syncthreads();
    }
    int excl = lsc[t] - orig;
    int node = b * RB + t;
    if (node < N) rowStart[node] = gbase + excl;
    if (b == 0 && t == 0) rowStart[N] = E;
    lcur[t] = excl;
    __syncthreads();
    i = 0;
    for (; i + 3 < rlen; i += 4) {
        unsigned e0 = (unsigned)ebuf[rbase + i];
        unsigned e1 = (unsigned)ebuf[rbase + i + 1];
        unsigned e2 = (unsigned)ebuf[rbase + i + 2];
        unsigned e3 = (unsigned)ebuf[rbase + i + 3];
        sorted[atomicAdd(&lcur[e0 >> 24], 1)] = (int)(e0 & 0xFFFFFFu);
        sorted[atomicAdd(&lcur[e1 >> 24], 1)] = (int)(e1 & 0xFFFFFFu);
        sorted[atomicAdd(&lcur[e2 >> 24], 1)] = (int)(e2 & 0xFFFFFFu);
        sorted[atomicAdd(&lcur[e3 >> 24], 1)] = (int)(e3 & 0xFFFFFFu);
    }
    for (; i < rlen; i++) {
        unsigned e = (unsigned)ebuf[rbase + i];
        sorted[atomicAdd(&lcur[e >> 24], 1)] = (int)(e & 0xFFFFFFu);
    }
    __syncthreads();
    const int total = lsc[255];
    for (int k = t; k < total; k += 256) esrc[gbase + k] = sorted[k];
}

// ---------------- fused agg: one wave per dst node (r16 version) ------------
__global__ __launch_bounds__(256) void agg_kernel(const int* __restrict__ rowStart,
                                                  const int* __restrict__ esrc,
                                                  const unsigned short* __restrict__ hb,
                                                  const float* __restrict__ el,
                                                  const float* __restrict__ er,
                                                  const float* __restrict__ bias,
                                                  float* __restrict__ out, int N) {
    const int wid = threadIdx.x >> 6;
    const int lane = threadIdx.x & 63;
    const int n = blockIdx.x * 4 + wid;
    if (n >= N) return;
    const int lg = lane & 15;
    const int grp = lane >> 4;
    const int head = lg >> 2;
    const float ern = er[n * NHEADS + head];
    const int beg = rowStart[n];
    const int end = rowStart[n + 1];

    float acc[8];
#pragma unroll
    for (int i = 0; i < 8; i++) acc[i] = 0.f;
    float den = 0.f;

#pragma unroll 4
    for (int j = beg + grp; j < end; j += 4) {
        int s = esrc[j];
        float x = el[s * NHEADS + head] + ern;
        x = x >= 0.f ? x : NEG * x;
        float sv = __expf(x);
        uint4 hv = *(const uint4*)&hb[(size_t)s * HF + lg * 8];
        acc[0] += sv * bf2f((unsigned short)(hv.x & 0xFFFFu));
        acc[1] += sv * bf2f((unsigned short)(hv.x >> 16));
        acc[2] += sv * bf2f((unsigned short)(hv.y & 0xFFFFu));
        acc[3] += sv * bf2f((unsigned short)(hv.y >> 16));
        acc[4] += sv * bf2f((unsigned short)(hv.z & 0xFFFFu));
        acc[5] += sv * bf2f((unsigned short)(hv.z >> 16));
        acc[6] += sv * bf2f((unsigned short)(hv.w & 0xFFFFu));
        acc[7] += sv * bf2f((unsigned short)(hv.w >> 16));
        den += sv;
    }

#pragma unroll
    for (int off = 16; off < 64; off <<= 1) {
#pragma unroll
        for (int i = 0; i < 8; i++) acc[i] += __shfl_xor(acc[i], off);
        den += __shfl_xor(den, off);
    }

    if (lane < 16) {
        float inv = 1.f / (den > 0.f ? den : 1.f);
        float4 b0 = *(const float4*)&bias[lg * 8];
        float4 b1 = *(const float4*)&bias[lg * 8 + 4];
        float4 o0, o1;
        o0.x = acc[0] * inv + b0.x; o0.y = acc[1] * inv + b0.y;
        o0.z = acc[2] * inv + b0.z; o0.w = acc[3] * inv + b0.w;
        o1.x = acc[4] * inv + b1.x; o1.y = acc[5] * inv + b1.y;
        o1.z = acc[6] * inv + b1.z; o1.w = acc[7] * inv + b1.w;
        *(float4*)&out[(size_t)n * HF + lg * 8] = o0;
        *(float4*)&out[(size_t)n * HF + lg * 8 + 4] = o1;
    }
}

extern "C" void kernel_launch(void* const* d_in, const int* in_sizes, int n_in,
                              void* d_out, int out_size, void* d_ws, size_t ws_size,
                              hipStream_t stream) {
    const float* feat = (const float*)d_in[0];
    const float* W    = (const float*)d_in[1];
    const float* al   = (const float*)d_in[2];
    const float* ar   = (const float*)d_in[3];
    const float* bias = (const float*)d_in[4];
    const int*   src  = (const int*)d_in[5];
    const int*   dst  = (const int*)d_in[6];
    const int N = in_sizes[0] / IN_F;
    const int E = in_sizes[5];
    float* out = (float*)d_out;

    const int nblk = (E + CHUNK - 1) / CHUNK;    // 250 for E=1.6M (must be <= 256)
    const int NBUCK = (N + RB - 1) / RB;         // 196 for N=50000 (must be <= NBP-1)
    const int GG = (N + 63) / 64;                // 782 gemm blocks

    unsigned short* hb = (unsigned short*)d_ws;              // N*128 bf16
    float* el       = (float*)(hb + (size_t)N * HF);         // N*4 f32
    float* er       = el + (size_t)N * NHEADS;               // N*4
    int* rowStart   = (int*)(er + (size_t)N * NHEADS);       // N+1
    int* esrc       = rowStart + (N + 1);                    // E
    int* ebuf       = esrc + E;                              // nblk*CHUNK
    int* cntArr     = ebuf + (size_t)nblk * CHUNK;           // nblk*NBP
    int* ofsArr     = cntArr + (size_t)nblk * NBP;           // nblk*NBP

    fused1_kernel<<<GG + nblk, 256, K1_SMEM, stream>>>(
        feat, W, al, ar, hb, el, er, src, dst, ebuf, cntArr, ofsArr, N, E, GG);
    bsort_kernel<<<NBUCK, 256, 0, stream>>>(ebuf, cntArr, ofsArr, rowStart, esrc, nblk, N, E);
    agg_kernel<<<(N + 3) / 4, 256, 0, stream>>>(rowStart, esrc, hb, el, er, bias, out, N);
}